// Round 11
// baseline (231.138 us; speedup 1.0000x reference)
//
#include <hip/hip_runtime.h>
#include <hip/hip_bf16.h>
#include <hip/hip_fp16.h>
#include <stdint.h>

#define CH 128
#define NCHUNK 512          // edge chunks for counting sort
#define MAXBKT 2048         // >= ceil(N/64)
#define NSLICE 8            // channel slices (16 ch each); slice s pinned to XCD s via blockIdx%8

typedef _Float16 f16x8 __attribute__((ext_vector_type(8)));
typedef float f32x4 __attribute__((ext_vector_type(4)));

static __device__ __forceinline__ float4 ld4(const float* p) {
    return *reinterpret_cast<const float4*>(p);
}

// ---------------- phase 0+1 fused: x -> fp16 SLICE-MAJOR copy + bucket histogram ---
// xh layout: [slice s][node][16 ch] (uint2 view: s*N*4 + node*4 + c, c=0..3)
__global__ __launch_bounds__(256) void k_bhist_cvt(const float* __restrict__ x,
        uint2* __restrict__ xh, int n, const int* __restrict__ dst,
        int* __restrict__ H, int nE, int nbkt, int chunkSz) {
    __shared__ int hist[MAXBKT];
    int c = blockIdx.x, tid = threadIdx.x;
    int gsz = gridDim.x * 256;
    int nw = n * NSLICE;
    for (int i = c * 256 + tid; i < nw; i += gsz) {
        int node = i >> 3, s = i & 7;
        const float* xp = x + (size_t)node * CH + s * 16;
        float4 v0 = ld4(xp), v1 = ld4(xp + 4), v2 = ld4(xp + 8), v3 = ld4(xp + 12);
        __half2 h0 = __floats2half2_rn(v0.x, v0.y);
        __half2 h1 = __floats2half2_rn(v0.z, v0.w);
        __half2 h2 = __floats2half2_rn(v1.x, v1.y);
        __half2 h3 = __floats2half2_rn(v1.z, v1.w);
        __half2 h4 = __floats2half2_rn(v2.x, v2.y);
        __half2 h5 = __floats2half2_rn(v2.z, v2.w);
        __half2 h6 = __floats2half2_rn(v3.x, v3.y);
        __half2 h7 = __floats2half2_rn(v3.z, v3.w);
        uint2* o = &xh[(size_t)s * n * 4 + (size_t)node * 4];
        o[0] = make_uint2(*reinterpret_cast<unsigned*>(&h0), *reinterpret_cast<unsigned*>(&h1));
        o[1] = make_uint2(*reinterpret_cast<unsigned*>(&h2), *reinterpret_cast<unsigned*>(&h3));
        o[2] = make_uint2(*reinterpret_cast<unsigned*>(&h4), *reinterpret_cast<unsigned*>(&h5));
        o[3] = make_uint2(*reinterpret_cast<unsigned*>(&h6), *reinterpret_cast<unsigned*>(&h7));
    }
    for (int i = tid; i < nbkt; i += 256) hist[i] = 0;
    __syncthreads();
    int s = c * chunkSz, e = min(s + chunkSz, nE);
    for (int i = s + tid; i < e; i += 256) atomicAdd(&hist[dst[i] >> 6], 1);
    __syncthreads();
    for (int i = tid; i < nbkt; i += 256) H[c * nbkt + i] = hist[i];
}

// ---------------- phase 2a: per-bucket totals ----------
__global__ void k_btot(const int* __restrict__ H, int* __restrict__ T, int nchunk, int nbkt) {
    __shared__ int sd[256];
    int b = blockIdx.x, tid = threadIdx.x;
    int v = 0;
    for (int c = tid; c < nchunk; c += 256) v += H[c * nbkt + b];
    sd[tid] = v;
    __syncthreads();
    for (int o = 128; o > 0; o >>= 1) {
        if (tid < o) sd[tid] += sd[tid + o];
        __syncthreads();
    }
    if (tid == 0) T[b] = sd[0];
}

// ---------------- phase 2b: exclusive scan of bucket totals -> base ----------
__global__ __launch_bounds__(1024) void k_bscan(const int* __restrict__ T,
                                                int* __restrict__ base, int nbkt) {
    __shared__ int ps[1024];
    int t = threadIdx.x;
    int a0 = (2 * t < nbkt) ? T[2 * t] : 0;
    int a1 = (2 * t + 1 < nbkt) ? T[2 * t + 1] : 0;
    ps[t] = a0 + a1;
    __syncthreads();
    for (int d = 1; d < 1024; d <<= 1) {
        int v = (t >= d) ? ps[t - d] : 0;
        __syncthreads();
        ps[t] += v;
        __syncthreads();
    }
    int excl = t ? ps[t - 1] : 0;
    if (2 * t < nbkt) base[2 * t] = excl;
    if (2 * t + 1 < nbkt) base[2 * t + 1] = excl + a0;
    if (t == 0) base[nbkt] = ps[1023];
}

// ---------------- phase 2c: per-(chunk,bucket) offsets, in place over H ----------
__global__ __launch_bounds__(512) void k_boff(int* H, const int* __restrict__ base,
                                              int nchunk, int nbkt) {
    __shared__ int sd[NCHUNK];
    int b = blockIdx.x, t = threadIdx.x;
    int v = (t < nchunk) ? H[t * nbkt + b] : 0;
    sd[t] = v;
    __syncthreads();
    for (int d = 1; d < NCHUNK; d <<= 1) {
        int tv = (t >= d) ? sd[t - d] : 0;
        __syncthreads();
        sd[t] += tv;
        __syncthreads();
    }
    if (t < nchunk) H[t * nbkt + b] = base[b] + sd[t] - v;
}

// ---------------- phase 3: bucket scatter (LDS cursors, plain global stores) ------
__global__ void k_bscatter(const int* __restrict__ src, const int* __restrict__ dst,
                           const int* __restrict__ H, int* __restrict__ sorted,
                           int nE, int nbkt, int chunkSz) {
    __shared__ int cur[MAXBKT];
    int c = blockIdx.x, tid = threadIdx.x;
    for (int i = tid; i < nbkt; i += 256) cur[i] = H[c * nbkt + i];
    __syncthreads();
    int s = c * chunkSz, e = min(s + chunkSz, nE);
    for (int i = s + tid; i < e; i += 256) {
        int d = dst[i];
        int pos = atomicAdd(&cur[d >> 6], 1);
        sorted[pos] = src[i] | ((d & 63) << 17);
    }
}

// ---------------- phase 4: within-bucket sort -> per-node CSR + offs ----------
// csr entries PRE-SCALED: csr[pos] = src << 2 (uint2 row base within a slice).
__global__ __launch_bounds__(256) void k_bsort2(const int* __restrict__ sorted,
        const int* __restrict__ base, int* __restrict__ csr, int* __restrict__ offs,
        int n, int nbkt, int nE) {
    __shared__ int hist[64];
    __shared__ int cur[64];
    int b = blockIdx.x, tid = threadIdx.x;
    if (tid < 64) hist[tid] = 0;
    __syncthreads();
    int s = base[b], e = base[b + 1];
    for (int i = s + tid; i < e; i += 256)
        atomicAdd(&hist[(sorted[i] >> 17) & 63], 1);
    __syncthreads();
    if (tid < 64) {
        int h0 = hist[tid], v = h0;
        for (int d = 1; d < 64; d <<= 1) {
            int t = __shfl_up(v, d, 64);
            if (tid >= d) v += t;
        }
        int excl = base[b] + v - h0;
        int node = b * 64 + tid;
        if (node < n) offs[node] = excl;
        cur[tid] = excl;
    }
    if (b == 0 && tid == 0) offs[n] = nE;
    __syncthreads();
    for (int i = s + tid; i < e; i += 256) {
        int p = sorted[i];
        int pos = atomicAdd(&cur[(p >> 17) & 63], 1);
        csr[pos] = (p & 0x1FFFF) << 2;   // pre-scaled uint2 index within slice
    }
}

// =========== GIN aggregate, XCD-pinned channel slices ===========
// slice = blockIdx%8 -> same XCD (round-robin dispatch): each XCD's L2 holds one
// 3.2MB slice permanently. 4-lane group per node (lane owns 4 ch), no cross-lane
// reduce. Output h16 slice-major [s][node][16].
static __device__ __forceinline__ void acc4(float4& a, uint2 v) {
    __half2 p0 = *reinterpret_cast<__half2*>(&v.x);
    __half2 p1 = *reinterpret_cast<__half2*>(&v.y);
    float2 f0 = __half22float2(p0), f1 = __half22float2(p1);
    a.x += f0.x; a.y += f0.y; a.z += f1.x; a.w += f1.y;
}

__global__ __launch_bounds__(256) void k_aggregate_s(const uint2* __restrict__ xv,
        const int* __restrict__ csr, const int* __restrict__ offs,
        uint2* __restrict__ h16, int n) {
    int s = blockIdx.x & (NSLICE - 1);
    int blk = blockIdx.x >> 3;           // 0 .. gridDim/8-1
    int nblk = gridDim.x >> 3;
    int tid = threadIdx.x;
    int g = tid >> 2;                    // 64 groups per block
    int c = tid & 3;                     // 4 ch (uint2) within slice
    size_t sb = (size_t)s * n * 4;       // slice base, uint2 units

    int chunk = (n + nblk - 1) / nblk;
    int node0 = blk * chunk;
    int node1 = min(node0 + chunk, n);

    for (int node = node0 + g; node < node1; node += 64) {
        float4 a0, a1 = make_float4(0.f, 0.f, 0.f, 0.f);
        {   // self-term
            uint2 v = xv[sb + (size_t)node * 4 + c];
            __half2 p0 = *reinterpret_cast<__half2*>(&v.x);
            __half2 p1 = *reinterpret_cast<__half2*>(&v.y);
            float2 f0 = __half22float2(p0), f1 = __half22float2(p1);
            a0 = make_float4(f0.x, f0.y, f1.x, f1.y);
        }
        int i = offs[node], e = offs[node + 1];
        for (; i + 3 < e; i += 4) {
            uint2 v0 = xv[sb + csr[i] + c];
            uint2 v1 = xv[sb + csr[i + 1] + c];
            uint2 v2 = xv[sb + csr[i + 2] + c];
            uint2 v3 = xv[sb + csr[i + 3] + c];
            acc4(a0, v0); acc4(a1, v1); acc4(a0, v2); acc4(a1, v3);
        }
        for (; i < e; ++i)
            acc4(a0, xv[sb + csr[i] + c]);
        a0.x += a1.x; a0.y += a1.y; a0.z += a1.z; a0.w += a1.w;
        __half2 o0 = __floats2half2_rn(a0.x, a0.y);
        __half2 o1 = __floats2half2_rn(a0.z, a0.w);
        unsigned long long ov =
            (unsigned long long)(*reinterpret_cast<unsigned*>(&o0)) |
            ((unsigned long long)(*reinterpret_cast<unsigned*>(&o1)) << 32);
        __builtin_nontemporal_store(ov,
            reinterpret_cast<unsigned long long*>(&h16[sb + (size_t)node * 4 + c]));
    }
}

// =========== MFMA GEMM: [nrows x 128] fp16 @ [128 x 128] -> out ===========
// aSliced: A is slice-major [s][node][16] (GEMM1 reading aggregate output).
// doStats: fp16 out (row-major) + per-channel sum/sumsq atomics (GEMM1).
// statsIn: BN finalize in prologue + relu(BN(a)) on A-load, fp32 out + relu (GEMM2).
__global__ __launch_bounds__(256) void k_mgemm(
        const _Float16* __restrict__ A, const float* __restrict__ W,
        const float* __restrict__ bias, _Float16* __restrict__ O16,
        float* __restrict__ O32, float* __restrict__ statsOut,
        const float* __restrict__ statsIn, const float* __restrict__ gamma,
        const float* __restrict__ beta, float invN, int nrows, int doStats, int aSliced) {
    __shared__ _Float16 WT[CH * CH];   // 32 KiB, swizzled
    __shared__ float sc_sh[2 * CH];
    int tid = threadIdx.x;
    for (int idx4 = tid * 4; idx4 < CH * CH; idx4 += 1024) {
        float4 wv = ld4(W + idx4);
        int k = idx4 >> 7, col = idx4 & 127;    // 4 consecutive cols, same k
        int s = k >> 3, j = k & 7;
#pragma unroll
        for (int q = 0; q < 4; ++q) {
            int c = col + q;
            WT[c * CH + ((s ^ (c & 7)) << 3) + j] =
                (_Float16)(q == 0 ? wv.x : q == 1 ? wv.y : q == 2 ? wv.z : wv.w);
        }
    }
    if (statsIn && tid < CH) {          // fused BN finalize (biased var, as in ref)
        float mean = statsIn[tid] * invN;
        float var = statsIn[CH + tid] * invN - mean * mean;
        float sc = gamma[tid] * rsqrtf(var + 1e-5f);
        sc_sh[tid] = sc;
        sc_sh[CH + tid] = beta[tid] - mean * sc;
    }
    __syncthreads();

    int wv = tid >> 6, lane = tid & 63;
    int lr = lane & 15;   // A-row / B-col / D-col within tile
    int lg = lane >> 4;   // k-group 0..3 (and D row-group)

    float bv[8];
#pragma unroll
    for (int ct = 0; ct < 8; ++ct) bv[ct] = bias[ct * 16 + lr];
    float ssum[8], ssq[8];
#pragma unroll
    for (int ct = 0; ct < 8; ++ct) { ssum[ct] = 0.f; ssq[ct] = 0.f; }

    int nchunks = (nrows + 63) >> 6;
    for (int chunk = blockIdx.x; chunk < nchunks; chunk += gridDim.x) {
        int row0 = chunk * 64 + wv * 16;
        int arow = min(row0 + lr, nrows - 1);
        f16x8 a[4];
        if (aSliced) {
#pragma unroll
            for (int kb = 0; kb < 4; ++kb) {
                int s = kb * 2 + (lg >> 1);   // ch = lg*8+kb*32 -> slice s, half (lg&1)
                a[kb] = *reinterpret_cast<const f16x8*>(
                    A + (size_t)s * nrows * 16 + (size_t)arow * 16 + (lg & 1) * 8);
            }
        } else {
            const _Float16* Ap = A + (size_t)arow * CH + lg * 8;
#pragma unroll
            for (int kb = 0; kb < 4; ++kb)
                a[kb] = *reinterpret_cast<const f16x8*>(Ap + kb * 32);
        }
        if (statsIn) {
#pragma unroll
            for (int kb = 0; kb < 4; ++kb) {
                int k0 = kb * 32 + lg * 8;
#pragma unroll
                for (int j = 0; j < 8; ++j) {
                    float f = (float)a[kb][j];
                    f = fmaxf(fmaf(f, sc_sh[k0 + j], sc_sh[CH + k0 + j]), 0.f);
                    a[kb][j] = (_Float16)f;
                }
            }
        }

        f32x4 acc[8];
#pragma unroll
        for (int ct = 0; ct < 8; ++ct) acc[ct] = (f32x4){0.f, 0.f, 0.f, 0.f};
#pragma unroll
        for (int ct = 0; ct < 8; ++ct) {
            int col = ct * 16 + lr;
            const _Float16* Wp = &WT[col * CH];
            int sw = (col & 7) << 3;
#pragma unroll
            for (int kb = 0; kb < 4; ++kb) {
                int s = kb * 4 + lg;
                f16x8 b = *reinterpret_cast<const f16x8*>(Wp + ((s << 3) ^ sw));
                acc[ct] = __builtin_amdgcn_mfma_f32_16x16x32_f16(a[kb], b, acc[ct], 0, 0, 0);
            }
        }

        // epilogue: D col = ct*16+lr, row = row0 + lg*4 + r
#pragma unroll
        for (int ct = 0; ct < 8; ++ct) {
            int col = ct * 16 + lr;
#pragma unroll
            for (int r = 0; r < 4; ++r) {
                int row = row0 + lg * 4 + r;
                if (row < nrows) {
                    float v = acc[ct][r] + bv[ct];
                    if (doStats) {
                        O16[(size_t)row * CH + col] = (_Float16)v;
                        ssum[ct] += v;
                        ssq[ct] += v * v;
                    } else {
                        O32[(size_t)row * CH + col] = fmaxf(v, 0.f);
                    }
                }
            }
        }
    }

    if (doStats) {
#pragma unroll
        for (int ct = 0; ct < 8; ++ct) {
            ssum[ct] += __shfl_xor(ssum[ct], 16, 64); ssum[ct] += __shfl_xor(ssum[ct], 32, 64);
            ssq[ct]  += __shfl_xor(ssq[ct], 16, 64);  ssq[ct]  += __shfl_xor(ssq[ct], 32, 64);
        }
        __syncthreads();           // WT dead; reuse as reduce scratch
        float* red = (float*)WT;
        if (lg == 0) {
#pragma unroll
            for (int ct = 0; ct < 8; ++ct) {
                red[wv * 128 + ct * 16 + lr] = ssum[ct];
                red[512 + wv * 128 + ct * 16 + lr] = ssq[ct];
            }
        }
        __syncthreads();
        if (tid < 128) {
            float s = 0.f, q = 0.f;
#pragma unroll
            for (int w = 0; w < 4; ++w) { s += red[w * 128 + tid]; q += red[512 + w * 128 + tid]; }
            atomicAdd(&statsOut[tid], s);
            atomicAdd(&statsOut[128 + tid], q);
        }
    }
}

extern "C" void kernel_launch(void* const* d_in, const int* in_sizes, int n_in,
                              void* d_out, int out_size, void* d_ws, size_t ws_size,
                              hipStream_t stream) {
    const float* x     = (const float*)d_in[0];
    const int*   ei    = (const int*)d_in[1];
    const float* W1    = (const float*)d_in[2];
    const float* b1    = (const float*)d_in[3];
    const float* gamma = (const float*)d_in[4];
    const float* beta  = (const float*)d_in[5];
    const float* W2    = (const float*)d_in[6];
    const float* b2    = (const float*)d_in[7];

    int N = in_sizes[0] / CH;   // 100000
    int E = in_sizes[1] / 2;    // 1600000
    const int* esrc = ei;
    const int* edst = ei + E;
    int nbkt = (N + 63) >> 6;   // 1563
    int chunkSz = (E + NCHUNK - 1) / NCHUNK;

    // d_out (51.2MB fp32) reuse:
    //   [0..3.2MB)  H[NCHUNK][nbkt]   (dead after scatter)
    //   [3.2..9.6MB) sorted[E]        (dead after bucket sort)
    //   [0..25.6MB) h16 fp16 slice-major (aggregate out, GEMM1 in)
    //   final: full fp32 output       (GEMM2)
    int* H      = (int*)d_out;
    int* sorted = (int*)((char*)d_out + (((size_t)NCHUNK * nbkt * 4 + 255) & ~(size_t)255));
    _Float16* h16 = (_Float16*)d_out;

    char* w = (char*)d_ws;
    auto take = [&](size_t bytes) {
        char* p = w;
        w += (bytes + 255) & ~(size_t)255;
        return p;
    };
    int*      csr    = (int*)take((size_t)E * 4);
    int*      T      = (int*)take((size_t)(nbkt + 1) * 4);
    int*      base   = (int*)take((size_t)(nbkt + 1) * 4);
    int*      offs   = (int*)take((size_t)(N + 1) * 4);
    float*    stats  = (float*)take(256 * 4);
    uint2*    xh     = (uint2*)take((size_t)N * CH * 2);   // fp16 x slice-major; reused as h1
    _Float16* h1     = (_Float16*)xh;

    (void)hipMemsetAsync(stats, 0, 256 * 4, stream);

    k_bhist_cvt<<<NCHUNK, 256, 0, stream>>>(x, xh, N, edst, H, E, nbkt, chunkSz);
    k_btot<<<nbkt, 256, 0, stream>>>(H, T, NCHUNK, nbkt);
    k_bscan<<<1, 1024, 0, stream>>>(T, base, nbkt);
    k_boff<<<nbkt, NCHUNK, 0, stream>>>(H, base, NCHUNK, nbkt);
    k_bscatter<<<NCHUNK, 256, 0, stream>>>(esrc, edst, H, sorted, E, nbkt, chunkSz);
    k_bsort2<<<nbkt, 256, 0, stream>>>(sorted, base, csr, offs, N, nbkt, E);
    k_aggregate_s<<<2048, 256, 0, stream>>>(xh, csr, offs, (uint2*)h16, N);
    // GEMM1: h16(sliced) @ W1 + b1 -> h1 (fp16 row-major, pre-BN) + channel stats
    k_mgemm<<<512, 256, 0, stream>>>(h16, W1, b1, h1, nullptr, stats,
                                     nullptr, nullptr, nullptr, 0.f, N, 1, 1);
    // GEMM2 (+fused BN finalize): relu(BN(h1)) @ W2 + b2 -> relu -> fp32 out
    k_mgemm<<<512, 256, 0, stream>>>(h1, W2, b2, nullptr, (float*)d_out, nullptr,
                                     stats, gamma, beta, 1.0f / (float)N, N, 0, 0);
}

// Round 13
// 204.730 us; speedup vs baseline: 1.1290x; 1.1290x over previous
//
#include <hip/hip_runtime.h>
#include <hip/hip_bf16.h>
#include <hip/hip_fp16.h>
#include <stdint.h>

#define CH 128
#define NCHUNK 512          // edge chunks for counting sort (== k_boff blockDim)
#define MAXBKT 2048         // >= ceil(N/64)

typedef _Float16 f16x8 __attribute__((ext_vector_type(8)));
typedef float f32x4 __attribute__((ext_vector_type(4)));

static __device__ __forceinline__ float4 ld4(const float* p) {
    return *reinterpret_cast<const float4*>(p);
}

static __device__ __forceinline__ void cvt_store_fp16(uint32_t* xh, int i, float4 v0, float4 v1) {
    __half2 h0 = __floats2half2_rn(v0.x, v0.y);
    __half2 h1 = __floats2half2_rn(v0.z, v0.w);
    __half2 h2 = __floats2half2_rn(v1.x, v1.y);
    __half2 h3 = __floats2half2_rn(v1.z, v1.w);
    uint4 o;
    o.x = *reinterpret_cast<unsigned*>(&h0);
    o.y = *reinterpret_cast<unsigned*>(&h1);
    o.z = *reinterpret_cast<unsigned*>(&h2);
    o.w = *reinterpret_cast<unsigned*>(&h3);
    reinterpret_cast<uint4*>(xh)[i] = o;
}

// ---------------- phase 0+1 fused: x->fp16 row-major copy + bucket histogram ------
__global__ __launch_bounds__(256) void k_bhist_cvt(const float* __restrict__ x,
        uint32_t* __restrict__ xh, int n8, const int* __restrict__ dst,
        int* __restrict__ H, int nE, int nbkt, int chunkSz) {
    __shared__ int hist[MAXBKT];
    int c = blockIdx.x, tid = threadIdx.x;
    int gsz = gridDim.x * 256;
    for (int i = c * 256 + tid; i < n8; i += gsz)
        cvt_store_fp16(xh, i, ld4(x + (size_t)i * 8), ld4(x + (size_t)i * 8 + 4));
    for (int i = tid; i < nbkt; i += 256) hist[i] = 0;
    __syncthreads();
    int s = c * chunkSz, e = min(s + chunkSz, nE);
    for (int i = s + tid; i < e; i += 256) atomicAdd(&hist[dst[i] >> 6], 1);
    __syncthreads();
    for (int i = tid; i < nbkt; i += 256) H[c * nbkt + i] = hist[i];
}

// ---------------- phase 2a: per-bucket totals ----------
__global__ void k_btot(const int* __restrict__ H, int* __restrict__ T, int nchunk, int nbkt) {
    __shared__ int sd[256];
    int b = blockIdx.x, tid = threadIdx.x;
    int v = 0;
    for (int c = tid; c < nchunk; c += 256) v += H[c * nbkt + b];
    sd[tid] = v;
    __syncthreads();
    for (int o = 128; o > 0; o >>= 1) {
        if (tid < o) sd[tid] += sd[tid + o];
        __syncthreads();
    }
    if (tid == 0) T[b] = sd[0];
}

// ---------------- phase 2b+2c fused: bucket-base prefix (from T) + per-chunk offs ---
// Each block b recomputes base[b] = sum T[0..b) itself (T is 6KB, L2-resident),
// writes base[b] for k_bsort2, then scans its H column in place.
__global__ __launch_bounds__(NCHUNK) void k_boff(int* H, const int* __restrict__ T,
                                                 int* __restrict__ base, int nchunk, int nbkt) {
    __shared__ int sd[NCHUNK];
    int b = blockIdx.x, t = threadIdx.x;
    int p = 0;
    for (int j = t; j < b; j += NCHUNK) p += T[j];
    sd[t] = p;
    __syncthreads();
    for (int o = NCHUNK / 2; o > 0; o >>= 1) {
        if (t < o) sd[t] += sd[t + o];
        __syncthreads();
    }
    int baseb = sd[0];
    __syncthreads();
    if (t == 0) {
        base[b] = baseb;
        if (b == nbkt - 1) base[nbkt] = baseb + T[b];
    }
    int v = (t < nchunk) ? H[t * nbkt + b] : 0;
    sd[t] = v;
    __syncthreads();
    for (int d = 1; d < NCHUNK; d <<= 1) {
        int tv = (t >= d) ? sd[t - d] : 0;
        __syncthreads();
        sd[t] += tv;
        __syncthreads();
    }
    if (t < nchunk) H[t * nbkt + b] = baseb + sd[t] - v;
}

// ---------------- phase 3: bucket scatter (LDS cursors, plain global stores) ------
__global__ void k_bscatter(const int* __restrict__ src, const int* __restrict__ dst,
                           const int* __restrict__ H, int* __restrict__ sorted,
                           int nE, int nbkt, int chunkSz) {
    __shared__ int cur[MAXBKT];
    int c = blockIdx.x, tid = threadIdx.x;
    for (int i = tid; i < nbkt; i += 256) cur[i] = H[c * nbkt + i];
    __syncthreads();
    int s = c * chunkSz, e = min(s + chunkSz, nE);
    for (int i = s + tid; i < e; i += 256) {
        int d = dst[i];
        int pos = atomicAdd(&cur[d >> 6], 1);
        sorted[pos] = src[i] | ((d & 63) << 17);
    }
}

// ---------------- phase 4: within-bucket sort -> per-node CSR + offs ----------
// csr entries PRE-SCALED: csr[pos] = src << 5 (uint2 row base, node*32).
__global__ __launch_bounds__(256) void k_bsort2(const int* __restrict__ sorted,
        const int* __restrict__ base, int* __restrict__ csr, int* __restrict__ offs,
        int n, int nbkt, int nE) {
    __shared__ int hist[64];
    __shared__ int cur[64];
    int b = blockIdx.x, tid = threadIdx.x;
    if (tid < 64) hist[tid] = 0;
    __syncthreads();
    int s = base[b], e = base[b + 1];
    for (int i = s + tid; i < e; i += 256)
        atomicAdd(&hist[(sorted[i] >> 17) & 63], 1);
    __syncthreads();
    if (tid < 64) {
        int h0 = hist[tid], v = h0;
        for (int d = 1; d < 64; d <<= 1) {
            int t = __shfl_up(v, d, 64);
            if (tid >= d) v += t;
        }
        int excl = base[b] + v - h0;
        int node = b * 64 + tid;
        if (node < n) offs[node] = excl;
        cur[tid] = excl;
    }
    if (b == 0 && tid == 0) offs[n] = nE;
    __syncthreads();
    for (int i = s + tid; i < e; i += 256) {
        int p = sorted[i];
        int pos = atomicAdd(&cur[(p >> 17) & 63], 1);
        csr[pos] = (p & 0x1FFFF) << 5;   // pre-scaled uint2 index
    }
}

// =========== GIN aggregate, 2 edges/wave, 8B/lane, deep unroll ===========
static __device__ __forceinline__ void acc4(float4& a, uint2 v) {
    __half2 p0 = *reinterpret_cast<__half2*>(&v.x);
    __half2 p1 = *reinterpret_cast<__half2*>(&v.y);
    float2 f0 = __half22float2(p0), f1 = __half22float2(p1);
    a.x += f0.x; a.y += f0.y; a.z += f1.x; a.w += f1.y;
}

__global__ void k_aggregate_h2(const uint2* __restrict__ xv,
        const int* __restrict__ csr, const int* __restrict__ offs,
        uint2* __restrict__ h16, int n) {
    int wid = (blockIdx.x * blockDim.x + threadIdx.x) >> 6;
    int lane = threadIdx.x & 63;
    int nw = (gridDim.x * blockDim.x) >> 6;
    int hf = lane >> 5;
    int l32 = lane & 31;
    for (int node = wid; node < n; node += nw) {
        float4 a0 = make_float4(0.f, 0.f, 0.f, 0.f), a1 = a0, a2 = a0, a3 = a0;
        if (hf == 0) acc4(a0, xv[(size_t)node * 32 + l32]);   // self-term (fp16 x)
        int s = offs[node], e = offs[node + 1];
        int i = s + hf;
        for (; i + 14 < e; i += 16) {   // 8 loads in flight per half-wave
            uint2 v0 = xv[csr[i]      + l32];
            uint2 v1 = xv[csr[i + 2]  + l32];
            uint2 v2 = xv[csr[i + 4]  + l32];
            uint2 v3 = xv[csr[i + 6]  + l32];
            uint2 v4 = xv[csr[i + 8]  + l32];
            uint2 v5 = xv[csr[i + 10] + l32];
            uint2 v6 = xv[csr[i + 12] + l32];
            uint2 v7 = xv[csr[i + 14] + l32];
            acc4(a0, v0); acc4(a1, v1); acc4(a2, v2); acc4(a3, v3);
            acc4(a0, v4); acc4(a1, v5); acc4(a2, v6); acc4(a3, v7);
        }
        for (; i + 6 < e; i += 8) {
            uint2 v0 = xv[csr[i]     + l32];
            uint2 v1 = xv[csr[i + 2] + l32];
            uint2 v2 = xv[csr[i + 4] + l32];
            uint2 v3 = xv[csr[i + 6] + l32];
            acc4(a0, v0); acc4(a1, v1); acc4(a2, v2); acc4(a3, v3);
        }
        for (; i < e; i += 2)
            acc4(a0, xv[csr[i] + l32]);
        a0.x += a1.x + a2.x + a3.x;
        a0.y += a1.y + a2.y + a3.y;
        a0.z += a1.z + a2.z + a3.z;
        a0.w += a1.w + a2.w + a3.w;
        a0.x += __shfl_xor(a0.x, 32, 64);
        a0.y += __shfl_xor(a0.y, 32, 64);
        a0.z += __shfl_xor(a0.z, 32, 64);
        a0.w += __shfl_xor(a0.w, 32, 64);
        if (hf == 0) {
            __half2 o0 = __floats2half2_rn(a0.x, a0.y);
            __half2 o1 = __floats2half2_rn(a0.z, a0.w);
            unsigned long long ov =
                (unsigned long long)(*reinterpret_cast<unsigned*>(&o0)) |
                ((unsigned long long)(*reinterpret_cast<unsigned*>(&o1)) << 32);
            __builtin_nontemporal_store(ov,
                reinterpret_cast<unsigned long long*>(&h16[(size_t)node * 32 + l32]));
        }
    }
}

// =========== MFMA GEMM: [nrows x 128] fp16 @ [128 x 128] -> out ===========
// v_mfma_f32_16x16x32_f16. W^T staged in LDS fp16, 16B-slot XOR swizzle.
// doStats: fp16 out + per-channel sum/sumsq atomics (GEMM1).
// statsIn: BN finalize in prologue + relu(BN(a)) on A-load, fp32 out + relu (GEMM2).
__global__ __launch_bounds__(256) void k_mgemm(
        const _Float16* __restrict__ A, const float* __restrict__ W,
        const float* __restrict__ bias, _Float16* __restrict__ O16,
        float* __restrict__ O32, float* __restrict__ statsOut,
        const float* __restrict__ statsIn, const float* __restrict__ gamma,
        const float* __restrict__ beta, float invN, int nrows, int doStats) {
    __shared__ _Float16 WT[CH * CH];   // 32 KiB, swizzled
    __shared__ float sc_sh[2 * CH];
    int tid = threadIdx.x;
    for (int idx4 = tid * 4; idx4 < CH * CH; idx4 += 1024) {
        float4 wv = ld4(W + idx4);
        int k = idx4 >> 7, col = idx4 & 127;    // 4 consecutive cols, same k
        int s = k >> 3, j = k & 7;
#pragma unroll
        for (int q = 0; q < 4; ++q) {
            int c = col + q;
            WT[c * CH + ((s ^ (c & 7)) << 3) + j] =
                (_Float16)(q == 0 ? wv.x : q == 1 ? wv.y : q == 2 ? wv.z : wv.w);
        }
    }
    if (statsIn && tid < CH) {          // fused BN finalize (biased var, as in ref)
        float mean = statsIn[tid] * invN;
        float var = statsIn[CH + tid] * invN - mean * mean;
        float sc = gamma[tid] * rsqrtf(var + 1e-5f);
        sc_sh[tid] = sc;
        sc_sh[CH + tid] = beta[tid] - mean * sc;
    }
    __syncthreads();

    int wv = tid >> 6, lane = tid & 63;
    int lr = lane & 15;   // A-row / B-col / D-col within tile
    int lg = lane >> 4;   // k-group 0..3 (and D row-group)

    float bv[8];
#pragma unroll
    for (int ct = 0; ct < 8; ++ct) bv[ct] = bias[ct * 16 + lr];
    float ssum[8], ssq[8];
#pragma unroll
    for (int ct = 0; ct < 8; ++ct) { ssum[ct] = 0.f; ssq[ct] = 0.f; }

    int nchunks = (nrows + 63) >> 6;
    for (int chunk = blockIdx.x; chunk < nchunks; chunk += gridDim.x) {
        int row0 = chunk * 64 + wv * 16;
        int arow = min(row0 + lr, nrows - 1);
        const _Float16* Ap = A + (size_t)arow * CH + lg * 8;
        f16x8 a[4];
#pragma unroll
        for (int kb = 0; kb < 4; ++kb)
            a[kb] = *reinterpret_cast<const f16x8*>(Ap + kb * 32);
        if (statsIn) {
#pragma unroll
            for (int kb = 0; kb < 4; ++kb) {
                int k0 = kb * 32 + lg * 8;
#pragma unroll
                for (int j = 0; j < 8; ++j) {
                    float f = (float)a[kb][j];
                    f = fmaxf(fmaf(f, sc_sh[k0 + j], sc_sh[CH + k0 + j]), 0.f);
                    a[kb][j] = (_Float16)f;
                }
            }
        }

        f32x4 acc[8];
#pragma unroll
        for (int ct = 0; ct < 8; ++ct) acc[ct] = (f32x4){0.f, 0.f, 0.f, 0.f};
#pragma unroll
        for (int ct = 0; ct < 8; ++ct) {
            int col = ct * 16 + lr;
            const _Float16* Wp = &WT[col * CH];
            int sw = (col & 7) << 3;
#pragma unroll
            for (int kb = 0; kb < 4; ++kb) {
                int s = kb * 4 + lg;
                f16x8 b = *reinterpret_cast<const f16x8*>(Wp + ((s << 3) ^ sw));
                acc[ct] = __builtin_amdgcn_mfma_f32_16x16x32_f16(a[kb], b, acc[ct], 0, 0, 0);
            }
        }

        // epilogue: D col = ct*16+lr, row = row0 + lg*4 + r
#pragma unroll
        for (int ct = 0; ct < 8; ++ct) {
            int col = ct * 16 + lr;
#pragma unroll
            for (int r = 0; r < 4; ++r) {
                int row = row0 + lg * 4 + r;
                if (row < nrows) {
                    float v = acc[ct][r] + bv[ct];
                    if (doStats) {
                        O16[(size_t)row * CH + col] = (_Float16)v;
                        ssum[ct] += v;
                        ssq[ct] += v * v;
                    } else {
                        O32[(size_t)row * CH + col] = fmaxf(v, 0.f);
                    }
                }
            }
        }
    }

    if (doStats) {
#pragma unroll
        for (int ct = 0; ct < 8; ++ct) {
            ssum[ct] += __shfl_xor(ssum[ct], 16, 64); ssum[ct] += __shfl_xor(ssum[ct], 32, 64);
            ssq[ct]  += __shfl_xor(ssq[ct], 16, 64);  ssq[ct]  += __shfl_xor(ssq[ct], 32, 64);
        }
        __syncthreads();           // WT dead; reuse as reduce scratch
        float* red = (float*)WT;
        if (lg == 0) {
#pragma unroll
            for (int ct = 0; ct < 8; ++ct) {
                red[wv * 128 + ct * 16 + lr] = ssum[ct];
                red[512 + wv * 128 + ct * 16 + lr] = ssq[ct];
            }
        }
        __syncthreads();
        if (tid < 128) {
            float s = 0.f, q = 0.f;
#pragma unroll
            for (int w = 0; w < 4; ++w) { s += red[w * 128 + tid]; q += red[512 + w * 128 + tid]; }
            atomicAdd(&statsOut[tid], s);
            atomicAdd(&statsOut[128 + tid], q);
        }
    }
}

extern "C" void kernel_launch(void* const* d_in, const int* in_sizes, int n_in,
                              void* d_out, int out_size, void* d_ws, size_t ws_size,
                              hipStream_t stream) {
    const float* x     = (const float*)d_in[0];
    const int*   ei    = (const int*)d_in[1];
    const float* W1    = (const float*)d_in[2];
    const float* b1    = (const float*)d_in[3];
    const float* gamma = (const float*)d_in[4];
    const float* beta  = (const float*)d_in[5];
    const float* W2    = (const float*)d_in[6];
    const float* b2    = (const float*)d_in[7];

    int N = in_sizes[0] / CH;   // 100000
    int E = in_sizes[1] / 2;    // 1600000
    const int* esrc = ei;
    const int* edst = ei + E;
    int nbkt = (N + 63) >> 6;   // 1563
    int chunkSz = (E + NCHUNK - 1) / NCHUNK;
    int n8 = N * CH / 8;

    // d_out (51.2MB fp32) is dead until the end; reuse it:
    //   [0..3.2MB)  H[NCHUNK][nbkt]   (dead after scatter)
    //   [3.2..9.6MB) sorted[E]        (dead after bucket sort)
    //   [0..25.6MB) h16 fp16          (written by aggregate, read by GEMM1)
    //   final: full fp32 output       (written by GEMM2)
    int* H      = (int*)d_out;
    int* sorted = (int*)((char*)d_out + (((size_t)NCHUNK * nbkt * 4 + 255) & ~(size_t)255));
    _Float16* h16 = (_Float16*)d_out;

    char* w = (char*)d_ws;
    auto take = [&](size_t bytes) {
        char* p = w;
        w += (bytes + 255) & ~(size_t)255;
        return p;
    };
    int*      csr    = (int*)take((size_t)E * 4);
    int*      T      = (int*)take((size_t)(nbkt + 1) * 4);
    int*      base   = (int*)take((size_t)(nbkt + 1) * 4);
    int*      offs   = (int*)take((size_t)(N + 1) * 4);
    float*    stats  = (float*)take(256 * 4);
    uint32_t* xh     = (uint32_t*)take((size_t)N * CH * 2);   // fp16 x; reused as h1
    _Float16* h1     = (_Float16*)xh;

    (void)hipMemsetAsync(stats, 0, 256 * 4, stream);

    k_bhist_cvt<<<NCHUNK, 256, 0, stream>>>(x, xh, n8, edst, H, E, nbkt, chunkSz);
    k_btot<<<nbkt, 256, 0, stream>>>(H, T, NCHUNK, nbkt);
    k_boff<<<nbkt, NCHUNK, 0, stream>>>(H, T, base, NCHUNK, nbkt);
    k_bscatter<<<NCHUNK, 256, 0, stream>>>(esrc, edst, H, sorted, E, nbkt, chunkSz);
    k_bsort2<<<nbkt, 256, 0, stream>>>(sorted, base, csr, offs, N, nbkt, E);
    k_aggregate_h2<<<4096, 256, 0, stream>>>((const uint2*)xh, csr, offs,
                                             (uint2*)h16, N);
    // GEMM1: h16 @ W1 + b1 -> h1 (fp16, pre-BN) + channel stats
    k_mgemm<<<512, 256, 0, stream>>>(h16, W1, b1, h1, nullptr, stats,
                                     nullptr, nullptr, nullptr, 0.f, N, 1);
    // GEMM2 (+fused BN finalize): relu(BN(h1)) @ W2 + b2 -> relu -> fp32 out
    k_mgemm<<<512, 256, 0, stream>>>(h1, W2, b2, nullptr, (float*)d_out, nullptr,
                                     stats, gamma, beta, 1.0f / (float)N, N, 0);
}